// Round 1
// 2709.164 us; speedup vs baseline: 1.4060x; 1.4060x over previous
//
#include <hip/hip_runtime.h>
#include <math.h>

#define DIM 2048
#define HIDDEN 5632
#define NE 8
#define NTOK 2048
#define NSLOT 4096

typedef __attribute__((ext_vector_type(8))) short bf16x8;
typedef __attribute__((ext_vector_type(4))) float f32x4;
typedef __attribute__((ext_vector_type(4))) unsigned int u32x4;

// ---- ws layout (bytes) ----
// [0, 65536)            scores   T*8 fp32
// [65536, 65568)        counts   8 int
// [65568, 65600)        cursor   8 int (unused now)
// [65600, 65664)        offsets  8 int (padded)
// [65664, 82048)        slot_tok 4096 int
// [82048, 98432)        slot_w   4096 fp32
// [131072, 16908288)    abuf     4096*2048 bf16 (16.8 MB)
// [16908288, 63045632)  hbuf     4096*5632 bf16 (46.1 MB)

__device__ __forceinline__ unsigned short f2bf(float f) {
    unsigned int u = __float_as_uint(f);
    unsigned int r = (u + 0x7fffu + ((u >> 16) & 1u)) >> 16;
    return (unsigned short)r;
}

__device__ __forceinline__ unsigned int cvt_pk_bf16(float lo, float hi) {
    unsigned int r;
    asm("v_cvt_pk_bf16_f32 %0, %1, %2" : "=v"(r) : "v"(lo), "v"(hi));
    return r;
}

#define MFMA(a, b, c) __builtin_amdgcn_mfma_f32_16x16x32_bf16(a, b, c, 0, 0, 0)

// ---------------- gating: scores[t][e] = x[t] . gate_w[e] (fp32) -------------
__global__ __launch_bounds__(256) void gate_kernel(
    const float* __restrict__ x, const float* __restrict__ gw,
    float* __restrict__ scores) {
    int t = blockIdx.x;
    const float* xr = x + (size_t)t * DIM;
    float acc[NE];
#pragma unroll
    for (int e = 0; e < NE; e++) acc[e] = 0.f;
    for (int d = threadIdx.x; d < DIM; d += 256) {
        float xv = xr[d];
#pragma unroll
        for (int e = 0; e < NE; e++) acc[e] += xv * gw[e * DIM + d];
    }
    __shared__ float red[256];
    for (int e = 0; e < NE; e++) {
        red[threadIdx.x] = acc[e];
        __syncthreads();
        for (int s = 128; s > 0; s >>= 1) {
            if (threadIdx.x < s) red[threadIdx.x] += red[threadIdx.x + s];
            __syncthreads();
        }
        if (threadIdx.x == 0) scores[t * NE + e] = red[0];
        __syncthreads();
    }
}

// ---------------- routing: top-2 + softmax + compaction (LDS atomics) --------
__global__ __launch_bounds__(256) void route_kernel(
    const float* __restrict__ scores, int* __restrict__ counts,
    int* __restrict__ offsets, int* __restrict__ slot_tok,
    float* __restrict__ slot_w) {
    __shared__ int lcnt[NE];
    __shared__ int lcur[NE];
    __shared__ int loff[NE];
    int tid = threadIdx.x;
    if (tid < NE) { lcnt[tid] = 0; lcur[tid] = 0; }
    __syncthreads();
    // pass 1: counts
    for (int t = tid; t < NTOK; t += 256) {
        const float* s = scores + t * NE;
        int i0 = 0; float v0 = s[0];
#pragma unroll
        for (int e = 1; e < NE; e++) { float v = s[e]; if (v > v0) { v0 = v; i0 = e; } }
        int i1 = -1; float v1 = -1e30f;
#pragma unroll
        for (int e = 0; e < NE; e++) {
            if (e == i0) continue;
            float v = s[e]; if (v > v1) { v1 = v; i1 = e; }
        }
        atomicAdd(&lcnt[i0], 1);
        atomicAdd(&lcnt[i1], 1);
    }
    __syncthreads();
    if (tid == 0) {
        int acc = 0;
        for (int e = 0; e < NE; e++) {
            loff[e] = acc;
            offsets[e] = acc;
            counts[e] = lcnt[e];
            acc += lcnt[e];
        }
    }
    __syncthreads();
    // pass 2: assign slots
    for (int t = tid; t < NTOK; t += 256) {
        const float* s = scores + t * NE;
        int i0 = 0; float v0 = s[0];
#pragma unroll
        for (int e = 1; e < NE; e++) { float v = s[e]; if (v > v0) { v0 = v; i0 = e; } }
        int i1 = -1; float v1 = -1e30f;
#pragma unroll
        for (int e = 0; e < NE; e++) {
            if (e == i0) continue;
            float v = s[e]; if (v > v1) { v1 = v; i1 = e; }
        }
        float e1 = expf(v1 - v0);
        float inv = 1.f / (1.f + e1);
        int s0 = loff[i0] + atomicAdd(&lcur[i0], 1);
        slot_tok[s0] = t; slot_w[s0] = inv;
        int s1 = loff[i1] + atomicAdd(&lcur[i1], 1);
        slot_tok[s1] = t; slot_w[s1] = e1 * inv;
    }
}

// ---------------- pack A: abuf[slot][d] = bf16(x[tok][d]) -------------------
__global__ __launch_bounds__(256) void pack_a_kernel(
    const float* __restrict__ x, const int* __restrict__ slot_tok,
    unsigned short* __restrict__ abuf) {
    int s = blockIdx.x;
    int tok = slot_tok[s];
    const float4* src = (const float4*)(x + (size_t)tok * DIM + threadIdx.x * 8);
    float4 a = src[0];
    float4 b = src[1];
    u32x4 r;
    r.x = cvt_pk_bf16(a.x, a.y);
    r.y = cvt_pk_bf16(a.z, a.w);
    r.z = cvt_pk_bf16(b.x, b.y);
    r.w = cvt_pk_bf16(b.z, b.w);
    *(u32x4*)(abuf + (size_t)s * DIM + threadIdx.x * 8) = r;
}

// ---------------- GEMM1: H = silu(Xg @ W1) * (Xg @ W3), bf16 out ------------
// grid (4, 88, 8), block 512 (8 waves). BM=512, BN=64/matrix, BK=64.
// A: reg fragments direct from abuf (bf16). B: LDS, fused fp32->bf16 transpose.
__global__ __launch_bounds__(512, 2) void gemm1_kernel(
    const unsigned short* __restrict__ abuf,
    const float* __restrict__ w1, const float* __restrict__ w3,
    const int* __restrict__ counts, const int* __restrict__ offsets,
    unsigned short* __restrict__ hbuf) {
    const int e = blockIdx.z;
    const int count = counts[e];
    const int m0 = blockIdx.x * 512;
    if (m0 >= count) return;
    const int n0 = blockIdx.y * 64;
    const int off = offsets[e];

    // rows 0..63: w1 cols n0..n0+63 ; rows 64..127: w3. 72-short (144B) stride.
    __shared__ __align__(16) unsigned short Bs[128][72];

    const int tid = threadIdx.x;
    const int wave = tid >> 6;
    const int lane = tid & 63;
    const int quad = lane >> 4;
    const int l16 = lane & 15;

    // B staging role: mat = wave&1, k-half bkh = wave>>1 (16 k each), col = lane
    const int bmat = wave & 1;
    const int bkh = wave >> 1;
    const float* wsel = bmat ? w3 : w1;
    const float* bsrc = wsel + (size_t)e * DIM * HIDDEN +
                        (size_t)(bkh * 16) * HIDDEN + n0 + lane;
    unsigned short* bdst = &Bs[bmat * 64 + lane][bkh * 16];

    // A fragment pointers per row-fragment (4 x 16 rows = 64 rows per wave)
    bool rfv[4];
    const unsigned short* aptr[4];
#pragma unroll
    for (int rf = 0; rf < 4; rf++) {
        int mbase = m0 + wave * 64 + rf * 16;
        rfv[rf] = (mbase < count);
        int slot = off + mbase + l16;
        if (slot > NSLOT - 1) slot = NSLOT - 1;
        aptr[rf] = abuf + (size_t)slot * DIM + quad * 8;
    }

    f32x4 accG[4][4], accU[4][4];
#pragma unroll
    for (int rf = 0; rf < 4; rf++)
#pragma unroll
        for (int cf = 0; cf < 4; cf++) {
            accG[rf][cf] = (f32x4)(0.f);
            accU[rf][cf] = (f32x4)(0.f);
        }

    float bv[16];
#pragma unroll
    for (int j = 0; j < 16; j++) bv[j] = bsrc[(size_t)j * HIDDEN];

    bf16x8 zfrag;
#pragma unroll
    for (int j = 0; j < 8; j++) zfrag[j] = 0;
    bf16x8 avA[2][4], avB[2][4];
#pragma unroll
    for (int rf = 0; rf < 4; rf++) {
        avA[0][rf] = zfrag; avA[1][rf] = zfrag;
        avB[0][rf] = zfrag; avB[1][rf] = zfrag;
        if (rfv[rf]) {
            avA[0][rf] = *(const bf16x8*)(aptr[rf]);
            avA[1][rf] = *(const bf16x8*)(aptr[rf] + 32);
        }
    }

#define G1_STEP(AVC, AVN, KT)                                                   \
    do {                                                                        \
        u32x4 wlo, whi;                                                         \
        wlo.x = cvt_pk_bf16(bv[0], bv[1]);  wlo.y = cvt_pk_bf16(bv[2], bv[3]);  \
        wlo.z = cvt_pk_bf16(bv[4], bv[5]);  wlo.w = cvt_pk_bf16(bv[6], bv[7]);  \
        whi.x = cvt_pk_bf16(bv[8], bv[9]);  whi.y = cvt_pk_bf16(bv[10], bv[11]);\
        whi.z = cvt_pk_bf16(bv[12], bv[13]);whi.w = cvt_pk_bf16(bv[14], bv[15]);\
        __syncthreads();                                                        \
        ((u32x4*)bdst)[0] = wlo;                                                \
        ((u32x4*)bdst)[1] = whi;                                                \
        {                                                                       \
            const int ktn = ((KT) + 64 < DIM) ? (KT) + 64 : (KT);               \
            _Pragma("unroll")                                                   \
            for (int j = 0; j < 16; j++) bv[j] = bsrc[(size_t)(ktn + j) * HIDDEN];\
            _Pragma("unroll")                                                   \
            for (int rf = 0; rf < 4; rf++) if (rfv[rf]) {                       \
                AVN[0][rf] = *(const bf16x8*)(aptr[rf] + ktn);                  \
                AVN[1][rf] = *(const bf16x8*)(aptr[rf] + ktn + 32);             \
            }                                                                   \
        }                                                                       \
        __syncthreads();                                                        \
        _Pragma("unroll")                                                       \
        for (int ks = 0; ks < 2; ks++) {                                        \
            _Pragma("unroll")                                                   \
            for (int cf = 0; cf < 4; cf++) {                                    \
                bf16x8 bG = *(const bf16x8*)&Bs[cf * 16 + l16][ks * 32 + quad * 8];      \
                bf16x8 bU = *(const bf16x8*)&Bs[64 + cf * 16 + l16][ks * 32 + quad * 8]; \
                _Pragma("unroll")                                               \
                for (int rf = 0; rf < 4; rf++) if (rfv[rf]) {                   \
                    accG[rf][cf] = MFMA(AVC[ks][rf], bG, accG[rf][cf]);         \
                    accU[rf][cf] = MFMA(AVC[ks][rf], bU, accU[rf][cf]);         \
                }                                                               \
            }                                                                   \
        }                                                                       \
    } while (0)

    for (int kt = 0; kt < DIM; kt += 128) {
        G1_STEP(avA, avB, kt);
        G1_STEP(avB, avA, kt + 64);
    }
#undef G1_STEP

    // epilogue: h = silu(g) * u -> bf16 hbuf
#pragma unroll
    for (int rf = 0; rf < 4; rf++) {
        if (!rfv[rf]) continue;
#pragma unroll
        for (int r = 0; r < 4; r++) {
            int m = m0 + wave * 64 + rf * 16 + quad * 4 + r;
            if (m < count) {
                unsigned short* hp = hbuf + (size_t)(off + m) * HIDDEN + n0 + l16;
#pragma unroll
                for (int cf = 0; cf < 4; cf++) {
                    float g = accG[rf][cf][r], u = accU[rf][cf][r];
                    float h = (g / (1.f + __expf(-g))) * u;
                    hp[cf * 16] = f2bf(h);
                }
            }
        }
    }
}

// ---------------- GEMM2: Y = H @ W2, weighted atomic scatter to out ---------
// grid (4, 32, 8), block 512. BM=512, BN=64, BK=64.
__global__ __launch_bounds__(512, 2) void gemm2_kernel(
    const unsigned short* __restrict__ hbuf, const float* __restrict__ w2,
    const int* __restrict__ counts, const int* __restrict__ offsets,
    const int* __restrict__ slot_tok, const float* __restrict__ slot_w,
    float* __restrict__ out) {
    const int e = blockIdx.z;
    const int count = counts[e];
    const int m0 = blockIdx.x * 512;
    if (m0 >= count) return;
    const int n0 = blockIdx.y * 64;
    const int off = offsets[e];

    __shared__ __align__(16) unsigned short Bs[64][72];
    __shared__ int toks[512];
    __shared__ float wts[512];

    const int tid = threadIdx.x;
    const int wave = tid >> 6;
    const int lane = tid & 63;
    const int quad = lane >> 4;
    const int l16 = lane & 15;

    {
        int m = m0 + tid;
        if (m < count) { toks[tid] = slot_tok[off + m]; wts[tid] = slot_w[off + m]; }
        else { toks[tid] = 0; wts[tid] = 0.f; }
    }

    // B staging: col = lane, k-eighth = wave (8 k each)
    const float* bsrc = w2 + (size_t)e * HIDDEN * DIM +
                        (size_t)(wave * 8) * DIM + n0 + lane;
    unsigned short* bdst = &Bs[lane][wave * 8];

    bool rfv[4];
    const unsigned short* aptr[4];
#pragma unroll
    for (int rf = 0; rf < 4; rf++) {
        int mbase = m0 + wave * 64 + rf * 16;
        rfv[rf] = (mbase < count);
        int slot = off + mbase + l16;
        if (slot > NSLOT - 1) slot = NSLOT - 1;
        aptr[rf] = hbuf + (size_t)slot * HIDDEN + quad * 8;
    }

    f32x4 acc[4][4];
#pragma unroll
    for (int rf = 0; rf < 4; rf++)
#pragma unroll
        for (int cf = 0; cf < 4; cf++) acc[rf][cf] = (f32x4)(0.f);

    float bv[8];
#pragma unroll
    for (int j = 0; j < 8; j++) bv[j] = bsrc[(size_t)j * DIM];

    bf16x8 zfrag;
#pragma unroll
    for (int j = 0; j < 8; j++) zfrag[j] = 0;
    bf16x8 avA[2][4], avB[2][4];
#pragma unroll
    for (int rf = 0; rf < 4; rf++) {
        avA[0][rf] = zfrag; avA[1][rf] = zfrag;
        avB[0][rf] = zfrag; avB[1][rf] = zfrag;
        if (rfv[rf]) {
            avA[0][rf] = *(const bf16x8*)(aptr[rf]);
            avA[1][rf] = *(const bf16x8*)(aptr[rf] + 32);
        }
    }

#define G2_STEP(AVC, AVN, KT)                                                   \
    do {                                                                        \
        u32x4 wv;                                                               \
        wv.x = cvt_pk_bf16(bv[0], bv[1]);                                       \
        wv.y = cvt_pk_bf16(bv[2], bv[3]);                                       \
        wv.z = cvt_pk_bf16(bv[4], bv[5]);                                       \
        wv.w = cvt_pk_bf16(bv[6], bv[7]);                                       \
        __syncthreads();                                                        \
        *(u32x4*)bdst = wv;                                                     \
        {                                                                       \
            const int ktn = ((KT) + 64 < HIDDEN) ? (KT) + 64 : (KT);            \
            _Pragma("unroll")                                                   \
            for (int j = 0; j < 8; j++) bv[j] = bsrc[(size_t)(ktn + j) * DIM];  \
            _Pragma("unroll")                                                   \
            for (int rf = 0; rf < 4; rf++) if (rfv[rf]) {                       \
                AVN[0][rf] = *(const bf16x8*)(aptr[rf] + ktn);                  \
                AVN[1][rf] = *(const bf16x8*)(aptr[rf] + ktn + 32);             \
            }                                                                   \
        }                                                                       \
        __syncthreads();                                                        \
        _Pragma("unroll")                                                       \
        for (int ks = 0; ks < 2; ks++) {                                        \
            _Pragma("unroll")                                                   \
            for (int cf = 0; cf < 4; cf++) {                                    \
                bf16x8 bf = *(const bf16x8*)&Bs[cf * 16 + l16][ks * 32 + quad * 8]; \
                _Pragma("unroll")                                               \
                for (int rf = 0; rf < 4; rf++) if (rfv[rf])                     \
                    acc[rf][cf] = MFMA(AVC[ks][rf], bf, acc[rf][cf]);           \
            }                                                                   \
        }                                                                       \
    } while (0)

    for (int kt = 0; kt < HIDDEN; kt += 128) {
        G2_STEP(avA, avB, kt);
        G2_STEP(avB, avA, kt + 64);
    }
#undef G2_STEP

    // epilogue: out[tok][n] += w * y
#pragma unroll
    for (int rf = 0; rf < 4; rf++) {
        if (!rfv[rf]) continue;
#pragma unroll
        for (int r = 0; r < 4; r++) {
            int ml = wave * 64 + rf * 16 + quad * 4 + r;
            int m = m0 + ml;
            if (m < count) {
                float wgt = wts[ml];
                float* op = out + (size_t)toks[ml] * DIM + n0 + l16;
#pragma unroll
                for (int cf = 0; cf < 4; cf++)
                    atomicAdd(op + cf * 16, wgt * acc[rf][cf][r]);
            }
        }
    }
}

extern "C" void kernel_launch(void* const* d_in, const int* in_sizes, int n_in,
                              void* d_out, int out_size, void* d_ws, size_t ws_size,
                              hipStream_t stream) {
    const float* x  = (const float*)d_in[0];
    const float* gw = (const float*)d_in[1];
    const float* w1 = (const float*)d_in[2];
    const float* w2 = (const float*)d_in[3];  // dict order is w1, w2, w3
    const float* w3 = (const float*)d_in[4];
    float* out = (float*)d_out;

    char* ws = (char*)d_ws;
    float* scores   = (float*)(ws + 0);
    int*   counts   = (int*)(ws + 65536);
    int*   offsets  = (int*)(ws + 65600);
    int*   slot_tok = (int*)(ws + 65664);
    float* slot_w   = (float*)(ws + 82048);
    unsigned short* abuf = (unsigned short*)(ws + 131072);
    unsigned short* hbuf = (unsigned short*)(ws + 16908288);

    hipMemsetAsync(d_out, 0, (size_t)out_size * sizeof(float), stream);

    gate_kernel<<<NTOK, 256, 0, stream>>>(x, gw, scores);
    route_kernel<<<1, 256, 0, stream>>>(scores, counts, offsets, slot_tok, slot_w);
    pack_a_kernel<<<NSLOT, 256, 0, stream>>>(x, slot_tok, abuf);
    gemm1_kernel<<<dim3(4, 88, 8), 512, 0, stream>>>(abuf, w1, w3, counts, offsets, hbuf);
    gemm2_kernel<<<dim3(4, 32, 8), 512, 0, stream>>>(hbuf, w2, counts, offsets,
                                                     slot_tok, slot_w, out);
}